// Round 7
// baseline (613.035 us; speedup 1.0000x reference)
//
#include <hip/hip_runtime.h>
#include <cstdint>
#include <cstddef>

#define N_NODES 8192
#define N_EDGES 262144
#define INPUT_DIM 512
#define HIDDEN 128
#define ALPHA 0.5f
#define EOS 1e-10f
#define BCAP 128

typedef float v4 __attribute__((ext_vector_type(4)));
typedef __attribute__((ext_vector_type(8))) short short8;
typedef __attribute__((ext_vector_type(4))) float floatx4;

__device__ inline unsigned f2bf2(float a, float b) {
    unsigned ua = __builtin_bit_cast(unsigned, a);
    unsigned ub = __builtin_bit_cast(unsigned, b);
    ua = (ua + 0x7FFFu + ((ua >> 16) & 1u)) >> 16;
    ub = (ub + 0x7FFFu + ((ub >> 16) & 1u)) & 0xFFFF0000u;
    return ua | ub;
}
__device__ inline short8 pack8(float4 x, float4 y) {
    union { unsigned u[4]; short8 s; } r;
    r.u[0] = f2bf2(x.x, x.y);
    r.u[1] = f2bf2(x.z, x.w);
    r.u[2] = f2bf2(y.x, y.y);
    r.u[3] = f2bf2(y.z, y.w);
    return r.s;
}

// K1: g[n] = sum_h relu(F[n]·W[h]+bemb[h]) * (Wedge[h]+Wedge[128+h])
// 512 blocks x 256 threads (4 waves). Block = 16 nodes; wave = 32 hidden
// (2 MFMA tiles) x full K=512. Fragments loaded DIRECTLY from global f32
// and packed to bf16 in registers — no LDS staging, no barriers in K-loop.
// Also zeroes cnt[] (saves a dispatch).
__global__ __launch_bounds__(256) void k1_g(
    const float* __restrict__ F, const float* __restrict__ W,
    const float* __restrict__ bemb, const float* __restrict__ Wedge,
    float* __restrict__ g, int* __restrict__ cnt)
{
    __shared__ float part[4][16];
    int tid = threadIdx.x;
    int gt = blockIdx.x * 256 + tid;
    if (gt < N_NODES) cnt[gt] = 0;

    int lane = tid & 63, wave = tid >> 6;
    int ml = lane & 15, q = lane >> 4;
    int node0 = blockIdx.x * 16;
    int h0 = wave * 32;

    const float* Ap  = &F[(size_t)(node0 + ml) * INPUT_DIM + q * 8];
    const float* Bp0 = &W[(size_t)(h0 + ml) * INPUT_DIM + q * 8];
    const float* Bp1 = &W[(size_t)(h0 + 16 + ml) * INPUT_DIM + q * 8];

    floatx4 acc0 = 0.f, acc1 = 0.f;
#pragma unroll 4
    for (int s = 0; s < 16; s++) {
        float4 a0  = *(const float4*)(Ap  + s * 32);
        float4 a1  = *(const float4*)(Ap  + s * 32 + 4);
        float4 b00 = *(const float4*)(Bp0 + s * 32);
        float4 b01 = *(const float4*)(Bp0 + s * 32 + 4);
        float4 b10 = *(const float4*)(Bp1 + s * 32);
        float4 b11 = *(const float4*)(Bp1 + s * 32 + 4);
        short8 a  = pack8(a0, a1);
        short8 b0 = pack8(b00, b01);
        short8 b1 = pack8(b10, b11);
        acc0 = __builtin_amdgcn_mfma_f32_16x16x32_bf16(a, b0, acc0, 0, 0, 0);
        acc1 = __builtin_amdgcn_mfma_f32_16x16x32_bf16(a, b1, acc1, 0, 0, 0);
    }
    // C/D: col(=hidden-in-tile)=ml, row(=node-in-tile)=q*4+reg
    float sr[4] = {0.f, 0.f, 0.f, 0.f};
#pragma unroll
    for (int t = 0; t < 2; t++) {
        int h = h0 + t * 16 + ml;
        float uu = Wedge[h] + Wedge[HIDDEN + h];
        float bb = bemb[h];
        floatx4 ac = t ? acc1 : acc0;
#pragma unroll
        for (int rg = 0; rg < 4; rg++) {
            float hv = ac[rg] + bb;
            sr[rg] += (hv > 0.f ? hv : 0.f) * uu;
        }
    }
#pragma unroll
    for (int m = 1; m < 16; m <<= 1) {
#pragma unroll
        for (int rg = 0; rg < 4; rg++) sr[rg] += __shfl_xor(sr[rg], m, 64);
    }
    if (ml == 0) {
#pragma unroll
        for (int rg = 0; rg < 4; rg++) part[wave][q * 4 + rg] = sr[rg];
    }
    __syncthreads();
    if (tid < 16)
        g[node0 + tid] = part[0][tid] + part[1][tid] + part[2][tid] + part[3][tid];
}

// K2: per-edge weight + packed bucket scatter: (col<<18)|idx and w as one int2.
__global__ __launch_bounds__(256) void k_edge(
    const int* __restrict__ edges, const float* __restrict__ noise,
    const float* __restrict__ g, const float* __restrict__ bedge,
    float* __restrict__ wlp, float* __restrict__ whp,
    int* __restrict__ cnt, int2* __restrict__ buck)
{
    int i = blockIdx.x * 256 + threadIdx.x;
    int e0 = edges[i], e1 = edges[N_EDGES + i];
    float raw = 0.5f * (g[e0] + g[e1]) + bedge[0];
    float eps = -0.9998f * noise[i] + 0.9999f;
    float gate = logf(eps) - log1pf(-eps) + raw;
    float w = 1.f / (1.f + expf(-gate));
    wlp[i] = w;
    whp[i] = 1.f - w;
    int pos = atomicAdd(&cnt[e0], 1);
    if (pos < BCAP) {
        int2 pw;
        pw.x = (e1 << 18) | i;
        pw.y = __builtin_bit_cast(int, w);
        buck[e0 * BCAP + pos] = pw;
    }
}

// K3: winner resolution + degrees -> inv factors. 2 rows/block.
// Winner = max packed value among same col (col in high bits, idx in low).
// Rewrites buck.x: winner -> col (>=0), loser -> -1 (w stays in buck.y).
__global__ __launch_bounds__(256) void k_deginv(
    const int* __restrict__ cnt, int2* __restrict__ buck,
    float* __restrict__ inv_lp, float* __restrict__ inv_hp)
{
    __shared__ int s_pv[2][BCAP];
    __shared__ float plp[4], php[4];
    int tid = threadIdx.x;
    int half = tid >> 7, lt = tid & 127;
    int r = blockIdx.x * 2 + half;
    int d = cnt[r]; if (d > BCAP) d = BCAP;
    int2 pw; pw.x = -1; pw.y = 0;
    if (lt < d) {
        pw = buck[r * BCAP + lt];
        s_pv[half][lt] = pw.x;
    }
    __syncthreads();
    float sl = 0.f, sh = 0.f;
    if (lt < d) {
        int pv = pw.x, c = pv >> 18;
        bool win = true;
        for (int j = 0; j < d; j++) {
            int o = s_pv[half][j];
            if ((o >> 18) == c && o > pv) { win = false; break; }
        }
        if (win) {
            float w = __builtin_bit_cast(float, pw.y);
            sl = w; sh = 1.f - w;
            pw.x = c;
        } else {
            pw.x = -1;
        }
        buck[r * BCAP + lt] = pw;
    }
#pragma unroll
    for (int m = 1; m < 64; m <<= 1) {
        sl += __shfl_xor(sl, m, 64);
        sh += __shfl_xor(sh, m, 64);
    }
    int wv = tid >> 6;
    if ((tid & 63) == 0) { plp[wv] = sl; php[wv] = sh; }
    __syncthreads();
    if (lt == 0) {
        float l = plp[half * 2] + plp[half * 2 + 1];
        float h = php[half * 2] + php[half * 2 + 1];
        inv_lp[r] = 1.f / (sqrtf(l + 1.f) + EOS);
        inv_hp[r] = 1.f / (sqrtf(h + 1.f) + EOS);
    }
}

// K4: one block per row, emits BOTH LP and HP rows. Col-bitmap + compact value
// list in LDS; zero chunks stored straight from registers. Plain (non-NT)
// stores this round — A/B vs round 6's nontemporal (fill kernel evidence).
__global__ __launch_bounds__(256) void k_fill(
    const int* __restrict__ cnt, const int2* __restrict__ buck,
    const float* __restrict__ inv_lp, const float* __restrict__ inv_hp,
    float* __restrict__ LP, float* __restrict__ HP)
{
    __shared__ unsigned bm[256];          // 8192 col bits
    __shared__ int   s_col[BCAP + 1];
    __shared__ float s_vlp[BCAP + 1];
    __shared__ float s_vhp[BCAP + 1];
    __shared__ int   s_d;
    int r = blockIdx.x, tid = threadIdx.x;
    bm[tid] = 0;
    int d = cnt[r]; if (d > BCAP) d = BCAP;
    float irl = inv_lp[r], irh = inv_hp[r];
    __syncthreads();
    int c = -1;
    if (tid < d) {
        int2 pw = buck[r * BCAP + tid];
        c = pw.x;
        s_col[tid] = c;
        if (c >= 0) {
            float w = __builtin_bit_cast(float, pw.y);
            float icl = inv_lp[c], ich = inv_hp[c];
            float diag = (c == r) ? 1.f : 0.f;
            s_vlp[tid] = (w + diag) * irl * icl;
            s_vhp[tid] = diag - ((1.f - w) + diag) * irh * ich * ALPHA;
            atomicOr(&bm[c >> 5], 1u << (c & 31));
        }
    }
    __syncthreads();
    if (tid == 0) {
        int dd = d;
        if (!((bm[r >> 5] >> (r & 31)) & 1u)) {   // no self-edge: background diagonal
            s_col[dd] = r; s_vlp[dd] = irl * irl; s_vhp[dd] = 1.0f;
            bm[r >> 5] |= 1u << (r & 31);
            dd++;
        }
        s_d = dd;
    }
    __syncthreads();
    int dd = s_d;
    float* LPr = LP + (size_t)r * N_NODES;
    float* HPr = HP + (size_t)r * N_NODES;
#pragma unroll
    for (int i = 0; i < 8; i++) {
        int ch = i * 256 + tid;               // chunk of 4 cols
        unsigned nib = (bm[ch >> 3] >> ((ch & 7) * 4)) & 0xFu;
        v4 lp = 0.f, hp = 0.f;
        if (nib) {
            for (int e = 0; e < dd; e++) {
                int cc = s_col[e];
                if (cc >= 0 && (cc >> 2) == ch) {
                    int sl = cc & 3;
                    ((float*)&lp)[sl] = s_vlp[e];
                    ((float*)&hp)[sl] = s_vhp[e];
                }
            }
        }
        *(v4*)&LPr[ch * 4] = lp;
        *(v4*)&HPr[ch * 4] = hp;
    }
}

extern "C" void kernel_launch(void* const* d_in, const int* in_sizes, int n_in,
                              void* d_out, int out_size, void* d_ws, size_t ws_size,
                              hipStream_t stream) {
    const float* F     = (const float*)d_in[0];
    const float* W     = (const float*)d_in[1];
    const float* bemb  = (const float*)d_in[2];
    const float* Wedge = (const float*)d_in[3];
    const float* bedge = (const float*)d_in[4];
    const float* noise = (const float*)d_in[5];
    const int*   edges = (const int*)d_in[6];

    const size_t N2 = (size_t)N_NODES * N_NODES;
    float* out = (float*)d_out;
    float* LP  = out;
    float* HP  = out + N2;
    float* wlp = HP + N2;
    float* whp = wlp + N_EDGES;

    // ws: g(32K) | cnt(32K) | inv_lp(32K) | inv_hp(32K) | buck(8M)
    char* ws = (char*)d_ws;
    float* g      = (float*)(ws);
    int*   cnt    = (int*)  (ws + 32768);
    float* inv_lp = (float*)(ws + 65536);
    float* inv_hp = (float*)(ws + 98304);
    int2*  buck   = (int2*) (ws + 131072);

    k1_g<<<512, 256, 0, stream>>>(F, W, bemb, Wedge, g, cnt);
    k_edge<<<N_EDGES / 256, 256, 0, stream>>>(edges, noise, g, bedge,
                                              wlp, whp, cnt, buck);
    k_deginv<<<N_NODES / 2, 256, 0, stream>>>(cnt, buck, inv_lp, inv_hp);
    k_fill<<<N_NODES, 256, 0, stream>>>(cnt, buck, inv_lp, inv_hp, LP, HP);
}